// Round 4
// baseline (321.616 us; speedup 1.0000x reference)
//
#include <hip/hip_runtime.h>
#include <cstdint>

#define NSTEP 1000
#define NELEM 45056          // 16 * 2816  (n*s = 16 slices of 64x44)
#define HW    2816           // 64 * 44
#define EPB   64             // elements per block == consumer wave width
#define PW    8              // producer waves per block
#define BLK   ((PW + 1) * 64)// 576 threads: 8 producer waves + 1 consumer wave
#define WIN   40             // k-steps per LDS window; NSTEP % WIN == 0, WIN % PW == 0
#define SPP   (WIN / PW)     // 5 k-steps per producer wave per window
#define NWIN  (NSTEP / WIN)  // 25

// ---------- compile-time fp64 DDIM schedule (bit-exact vs np.linspace+cumprod) ----------
struct AlphTab { float a[NSTEP + 1]; };

constexpr AlphTab make_alph() {
    AlphTab t{};
    t.a[0] = 1.0f;
    double alph = 1.0;
    const double start = 1e-4, stop = 0.02;
    const double step = (stop - start) / 999.0;
    for (int i = 0; i < NSTEP; ++i) {
        double beta = (i == NSTEP - 1) ? stop : ((double)i * step + start);
        alph *= (1.0 - beta);
        t.a[i + 1] = (float)alph;
    }
    return t;
}
constexpr AlphTab ALPH = make_alph();

// ---------- Threefry-2x32-20 (partitionable-mode usage: ctr=(0,j), out = x0^x1) ----------
__device__ __forceinline__ void tf20(uint32_t K0, uint32_t K1, uint32_t K2,
                                     uint32_t& x0, uint32_t& x1) {
    x0 += K0; x1 += K1;
#define TFR(r) { x0 += x1; x1 = ((x1 << r) | (x1 >> (32 - r))); x1 ^= x0; }
    TFR(13) TFR(15) TFR(26) TFR(6)
    x0 += K1; x1 += K2 + 1u;
    TFR(17) TFR(29) TFR(16) TFR(24)
    x0 += K2; x1 += K0 + 2u;
    TFR(13) TFR(15) TFR(26) TFR(6)
    x0 += K0; x1 += K1 + 3u;
    TFR(17) TFR(29) TFR(16) TFR(24)
    x0 += K1; x1 += K2 + 4u;
    TFR(13) TFR(15) TFR(26) TFR(6)
    x0 += K2; x1 += K0 + 5u;
#undef TFR
}

// Two independent Threefry chains, source-interleaved for ILP: the serial
// add->rotate->xor chain of one stream hides under the other's latency.
__device__ __forceinline__ void tf20x2(uint32_t A0, uint32_t A1, uint32_t A2,
                                       uint32_t& ax0, uint32_t& ax1,
                                       uint32_t B0, uint32_t B1, uint32_t B2,
                                       uint32_t& bx0, uint32_t& bx1) {
    ax0 += A0; ax1 += A1; bx0 += B0; bx1 += B1;
#define TFR2(r) { ax0 += ax1; bx0 += bx1; \
                  ax1 = ((ax1 << r) | (ax1 >> (32 - r))); ax1 ^= ax0; \
                  bx1 = ((bx1 << r) | (bx1 >> (32 - r))); bx1 ^= bx0; }
    TFR2(13) TFR2(15) TFR2(26) TFR2(6)
    ax0 += A1; ax1 += A2 + 1u;  bx0 += B1; bx1 += B2 + 1u;
    TFR2(17) TFR2(29) TFR2(16) TFR2(24)
    ax0 += A2; ax1 += A0 + 2u;  bx0 += B2; bx1 += B0 + 2u;
    TFR2(13) TFR2(15) TFR2(26) TFR2(6)
    ax0 += A0; ax1 += A1 + 3u;  bx0 += B0; bx1 += B1 + 3u;
    TFR2(17) TFR2(29) TFR2(16) TFR2(24)
    ax0 += A1; ax1 += A2 + 4u;  bx0 += B1; bx1 += B2 + 4u;
    TFR2(13) TFR2(15) TFR2(26) TFR2(6)
    ax0 += A2; ax1 += A0 + 5u;  bx0 += B2; bx1 += B0 + 5u;
#undef TFR2
}

// bits -> erfinv(u). Dual-poly, single select; wave-uniform skip of the far
// branch (P(any of 64 lanes far) ~ 19%). Bit-identical to the reference poly.
__device__ __forceinline__ float bits_to_erfinv(uint32_t bits) {
    const float f2 = __uint_as_float((bits >> 9) | 0x3F800000u) - 1.0f;
    const float u  = f2 * 2.0f - 0.99999994f;
    const float t1 = (1.0f - u) * (1.0f + u);
    const float w  = __log2f(t1) * -0.6931472f;
    const bool  lt = w < 5.0f;

    const float wwn = w - 2.5f;
    float pn =           2.81022636e-08f;
    pn = fmaf(pn, wwn,   3.43273939e-07f);
    pn = fmaf(pn, wwn,  -3.5233877e-06f);
    pn = fmaf(pn, wwn,  -4.39150654e-06f);
    pn = fmaf(pn, wwn,   0.00021858087f);
    pn = fmaf(pn, wwn,  -0.00125372503f);
    pn = fmaf(pn, wwn,  -0.00417768164f);
    pn = fmaf(pn, wwn,   0.246640727f);
    pn = fmaf(pn, wwn,   1.50140941f);

    float p = pn;
    if (__any(!lt)) {                                 // wave-uniform branch
        const float sw  = __builtin_amdgcn_sqrtf(w);  // w >= 0 always
        const float wwf = sw - 3.0f;
        float pf =           -0.000200214257f;
        pf = fmaf(pf, wwf,    0.000100950558f);
        pf = fmaf(pf, wwf,    0.00134934322f);
        pf = fmaf(pf, wwf,   -0.00367342844f);
        pf = fmaf(pf, wwf,    0.00573950773f);
        pf = fmaf(pf, wwf,   -0.0076224613f);
        pf = fmaf(pf, wwf,    0.00943887047f);
        pf = fmaf(pf, wwf,    1.00167406f);
        pf = fmaf(pf, wwf,    2.83297682f);
        p = lt ? pn : pf;
    }
    return p * u;
}

// one producer wave's share of a window: SPP k-steps, processed in
// ILP-pairs of two independent threefry+erfinv streams.
__device__ __forceinline__ void produce_window(const uint4* __restrict__ tabP,
                                               float* __restrict__ db,
                                               int kbase, int wid, int lane,
                                               int j, float sT) {
#pragma unroll
    for (int s = 0; s + 1 < SPP; s += 2) {
        const int kka = wid + s * PW;
        const int kkb = kka + PW;
        const uint4 ta = tabP[kbase + kka];
        const uint4 tb = tabP[kbase + kkb];
        uint32_t ax0 = 0u, ax1 = (uint32_t)j;
        uint32_t bx0 = 0u, bx1 = (uint32_t)j;
        tf20x2(ta.z, ta.w, ta.z ^ ta.w ^ 0x1BD11BDAu, ax0, ax1,
               tb.z, tb.w, tb.z ^ tb.w ^ 0x1BD11BDAu, bx0, bx1);
        const float eia = bits_to_erfinv(ax0 ^ ax1);
        const float eib = bits_to_erfinv(bx0 ^ bx1);
        db[kka * EPB + lane] =
            fmaf(__uint_as_float(ta.x), eia, __uint_as_float(ta.y) * sT);
        db[kkb * EPB + lane] =
            fmaf(__uint_as_float(tb.x), eib, __uint_as_float(tb.y) * sT);
    }
    if constexpr (SPP & 1) {            // odd tail
        const int kk = wid + (SPP - 1) * PW;
        const uint4 ta = tabP[kbase + kk];
        uint32_t x0 = 0u, x1 = (uint32_t)j;
        tf20(ta.z, ta.w, ta.z ^ ta.w ^ 0x1BD11BDAu, x0, x1);
        const float ei = bits_to_erfinv(x0 ^ x1);
        db[kk * EPB + lane] =
            fmaf(__uint_as_float(ta.x), ei, __uint_as_float(ta.y) * sT);
    }
}

// =====================================================================
// Fused producer-consumer kernel.
//   grid = NELEM/EPB = 704 blocks x 576 threads (9 waves).
//   waves 0..7 (producers): threefry+erfinv noise, 2-way ILP pairs.
//   wave 8 (consumer): serial DDIM scan, LDS -> out.
// LDS: tabP 16K + tabC 8K + dbuf 20K = 44.25 KB -> 3 blocks/CU.
// __launch_bounds__(576, 6): VGPR headroom (~85) so the paired chains
// stay interleaved instead of being serialized into 36 regs.
// =====================================================================
__global__ __launch_bounds__(BLK, 6)
void fused_kernel(const float* __restrict__ skes,
                  const float* __restrict__ silT,
                  const float* __restrict__ wskes,
                  const float* __restrict__ wsil_p,
                  const float* __restrict__ tsc_p,
                  float* __restrict__ out) {
    __shared__ __align__(16) uint4    tabP[NSTEP];   // {c1s, e, k0, k1}
    __shared__ __align__(8)  uint2    tabC[NSTEP];   // {A, temb*2log2e}
    __shared__ __align__(16) float    dbuf[2][WIN][EPB];

    const float wsil = wsil_p[0];
    const float tsc  = tsc_p[0];
    const float L2E2 = 2.8853900817779268f;      // 2*log2(e)

    // ---- one-time schedule init: 2 rows/thread ----
    for (int k = (int)threadIdx.x; k < NSTEP; k += BLK) {
        const int t = 999 - k;
        const float at  = ALPH.a[t + 1];
        const float atn = ALPH.a[t];
        const float c1 = 0.1f * sqrtf((1.0f - at / atn) * (1.0f - atn) / (1.0f - at));
        const float c2 = sqrtf(fmaxf(1.0f - atn - c1 * c1, 0.0f));
        const float rs = 1.0f / sqrtf(1.0f - at);
        const float A  = sqrtf(atn) - c2 * sqrtf(at) * rs;
        const float e  = c2 * rs;
        const float temb = tsc * ((float)t / 1000.0f);
        // fold_in(key(42), t): key <- threefry(key=[0,42], ctr=[0,t])
        uint32_t k0 = 0u, k1 = (uint32_t)t;
        tf20(0u, 42u, 0x1BD11BDAu ^ 42u, k0, k1);
        tabP[k]  = make_uint4(__float_as_uint(c1 * 1.4142135f),
                              __float_as_uint(e), k0, k1);
        tabC[k]  = make_uint2(__float_as_uint(A), __float_as_uint(temb * L2E2));
    }

    const int wid  = (int)(threadIdx.x >> 6);
    const int lane = (int)(threadIdx.x & 63);
    const int j    = (int)(blockIdx.x * EPB) + lane;

    const float sT = silT[j];

    // consumer-only per-lane state
    float cc2 = 0.0f, ws2 = 0.0f, sil = 0.0f;
    if (wid == PW) {
        const int ns = j / HW;
        const int hw = j - ns * HW;
        const int n  = ns >> 3;
        const int ss = ns & 7;
        const float* sk = skes + (size_t)((n * 3) * 8 + ss) * HW + hw;
        const float w0 = wskes[0], w1 = wskes[1], w2 = wskes[2];
        const float cond = fmaf(w2, sk[2 * 8 * HW], fmaf(w1, sk[8 * HW], w0 * sk[0]));
        cc2 = cond * L2E2;
        ws2 = wsil * L2E2;
        sil = sT;
    }

    __syncthreads();   // tab ready

    // ---- prologue: producers fill window 0 into dbuf[0] ----
    if (wid < PW) {
        produce_window(tabP, &dbuf[0][0][0], 0, wid, lane, j, sT);
    }
    __syncthreads();   // window 0 ready

    float* op = out + j;

    for (int w = 0; w < NWIN; ++w) {
        if (wid < PW) {
            // ---- producers: fill window w+1 into the other buffer ----
            if (w + 1 < NWIN) {
                produce_window(tabP, &dbuf[(w + 1) & 1][0][0],
                               (w + 1) * WIN, wid, lane, j, sT);
            }
        } else {
            // ---- consumer: serial scan over window w ----
            const float* db = &dbuf[w & 1][0][0];
            const int kbase = w * WIN;
#pragma unroll 4
            for (int kk = 0; kk < WIN; ++kk) {
                const uint2 tt = tabC[kbase + kk];
                const float A  = __uint_as_float(tt.x);
                const float tb = __uint_as_float(tt.y);
                const float e2 = __builtin_amdgcn_exp2f(fmaf(ws2, sil, cc2 + tb));
                const float r  = __builtin_amdgcn_rcpf(e2 + 1.0f);
                const float s0 = fmaf(-2.0f, r, 1.0f);
                *op = s0; op += NELEM;
                sil = fmaf(A, s0, db[kk * EPB + lane]);
            }
        }
        __syncthreads();   // window w consumed / window w+1 ready
    }
}

extern "C" void kernel_launch(void* const* d_in, const int* in_sizes, int n_in,
                              void* d_out, int out_size, void* d_ws, size_t ws_size,
                              hipStream_t stream) {
    const float* skes = (const float*)d_in[0];
    const float* silT = (const float*)d_in[1];
    const float* wsk  = (const float*)d_in[2];
    const float* wsil = (const float*)d_in[3];
    const float* tsc  = (const float*)d_in[4];
    float* out = (float*)d_out;
    (void)in_sizes; (void)n_in; (void)out_size; (void)d_ws; (void)ws_size;

    dim3 grid(NELEM / EPB), block(BLK);
    hipLaunchKernelGGL(fused_kernel, grid, block, 0, stream,
                       skes, silT, wsk, wsil, tsc, out);
}